// Round 4
// baseline (91.597 us; speedup 1.0000x reference)
//
#include <hip/hip_runtime.h>

typedef unsigned short ushort_t;
typedef unsigned int uint_t;

constexpr int BSZ = 32;
constexpr int CH  = 64;
constexpr int HW  = 32 * 128;   // 4096
constexpr int NP  = 512;
constexpr float EPS = 1e-8f;

using short8 = __attribute__((ext_vector_type(8))) short;   // 8 bf16 (4 VGPRs)
using f32x4  = __attribute__((ext_vector_type(4))) float;

__device__ __forceinline__ ushort_t f2bf(float f) {   // fp32 -> bf16 RNE
    uint_t u = __builtin_bit_cast(uint_t, f);
    u += 0x7FFFu + ((u >> 16) & 1u);
    return (ushort_t)(u >> 16);
}
__device__ __forceinline__ float bf2f(ushort_t b) {
    uint_t u = ((uint_t)b) << 16;
    return __builtin_bit_cast(float, u);
}
__device__ __forceinline__ float tanh_fast(float x) {
    // tanh(x) = 1 - 2/(exp(2x)+1); exact at +-inf, ~1e-7 rel error.
    float e = __expf(x + x);
    float r = __builtin_amdgcn_rcpf(e + 1.0f);
    return fmaf(-2.0f, r, 1.0f);
}

// K0: split W into bf16 hi/lo; fold Ua_b+query into QB.
__global__ __launch_bounds__(256) void k_prep(
    const float* __restrict__ Ua_w, const float* __restrict__ Ua_b,
    const float* __restrict__ query,
    ushort_t* __restrict__ Whi, ushort_t* __restrict__ Wlo,
    float* __restrict__ QB)
{
    const int i = blockIdx.x * 256 + threadIdx.x;
    if (i < NP * CH) {
        float x = Ua_w[i];
        ushort_t h = f2bf(x);
        Whi[i] = h;
        Wlo[i] = f2bf(x - bf2f(h));
    }
    if (i < BSZ * NP) {
        QB[i] = query[i] + Ua_b[i & (NP - 1)];
    }
}

// K1: e_t[b,p] = sum_o Va_w[o] * tanh( W[o,:].key[b,:,p] + QB[b,o] )
// MFMA 16x16x32 bf16, 3-pass bf16 split. Wave owns 32 positions (nt=2) so the
// grid is 1024 blocks -> 16 waves/CU (round-3 counters: 512 blocks capped
// occupancy at 18.8% and every pipe idled). QB is folded into the accumulator
// init instead of added post-MFMA.
__global__ __launch_bounds__(256, 4) void k_scores(
    const float* __restrict__ key,
    const ushort_t* __restrict__ Whi, const ushort_t* __restrict__ Wlo,
    const float* __restrict__ QB, const float* __restrict__ Va_w,
    float* __restrict__ e_t)
{
    const int bx = blockIdx.x;            // 0..1023
    const int b  = bx >> 5;               // batch (32 blocks per batch)
    const int wv = threadIdx.x >> 6;
    const int l  = threadIdx.x & 63;
    const int lm = l & 15;                // col-in-tile (A row / B,C col)
    const int kg = l >> 4;                // k-group
    const int p0 = (bx & 31) * 128 + wv * 32;   // wave's first position

    // ---- load + bf16-split this wave's B = key[b, :, p0..p0+31] ----
    // B-frag layout: col = l&15, k = kg*8 + j  (within each K=32 step)
    short8 Bh[2][2], Bl[2][2];
    const float* kb = key + (size_t)b * CH * HW;
#pragma unroll
    for (int nt = 0; nt < 2; ++nt) {
#pragma unroll
        for (int ks = 0; ks < 2; ++ks) {
#pragma unroll
            for (int j = 0; j < 8; ++j) {
                float x = kb[(size_t)(ks * 32 + kg * 8 + j) * HW + (p0 + nt * 16 + lm)];
                ushort_t h = f2bf(x);
                Bh[nt][ks][j] = (short)h;
                Bl[nt][ks][j] = (short)f2bf(x - bf2f(h));
            }
        }
    }

    const float* qbp = QB + b * NP;
    float ew[2] = {0.0f, 0.0f};

#pragma unroll 2
    for (int mt = 0; mt < NP / 16; ++mt) {
        // A-frags: row = l&15, k = kg*8+j, contiguous 8 bf16 -> one dwordx4
        const int arow = (mt * 16 + lm) * CH + kg * 8;
        const short8 Ah0 = *(const short8*)(Whi + arow);
        const short8 Ah1 = *(const short8*)(Whi + arow + 32);
        const short8 Al0 = *(const short8*)(Wlo + arow);
        const short8 Al1 = *(const short8*)(Wlo + arow + 32);

        // C/D layout: col = l&15, row = kg*4 + r  ->  o = mt*16 + kg*4 + r
        // init acc with QB (saves the post-MFMA add)
        const f32x4 qb = *(const f32x4*)(qbp + mt * 16 + kg * 4);
        const f32x4 vw = *(const f32x4*)(Va_w + mt * 16 + kg * 4);

        f32x4 acc[2];
#pragma unroll
        for (int nt = 0; nt < 2; ++nt) acc[nt] = qb;
#pragma unroll
        for (int nt = 0; nt < 2; ++nt) {
            acc[nt] = __builtin_amdgcn_mfma_f32_16x16x32_bf16(Ah0, Bh[nt][0], acc[nt], 0, 0, 0);
            acc[nt] = __builtin_amdgcn_mfma_f32_16x16x32_bf16(Ah1, Bh[nt][1], acc[nt], 0, 0, 0);
            acc[nt] = __builtin_amdgcn_mfma_f32_16x16x32_bf16(Ah0, Bl[nt][0], acc[nt], 0, 0, 0);
            acc[nt] = __builtin_amdgcn_mfma_f32_16x16x32_bf16(Ah1, Bl[nt][1], acc[nt], 0, 0, 0);
            acc[nt] = __builtin_amdgcn_mfma_f32_16x16x32_bf16(Al0, Bh[nt][0], acc[nt], 0, 0, 0);
            acc[nt] = __builtin_amdgcn_mfma_f32_16x16x32_bf16(Al1, Bh[nt][1], acc[nt], 0, 0, 0);
        }

#pragma unroll
        for (int nt = 0; nt < 2; ++nt) {
#pragma unroll
            for (int r = 0; r < 4; ++r) {
                ew[nt] = fmaf(vw[r], tanh_fast(acc[nt][r]), ew[nt]);
            }
        }
    }

    // reduce over the 4 k-groups (rows live in lanes l, l^16, l^32, l^48)
#pragma unroll
    for (int nt = 0; nt < 2; ++nt) {
        ew[nt] += __shfl_xor(ew[nt], 16, 64);
        ew[nt] += __shfl_xor(ew[nt], 32, 64);
    }
    if (kg == 0) {
#pragma unroll
        for (int nt = 0; nt < 2; ++nt)
            e_t[(size_t)b * HW + p0 + nt * 16 + lm] = ew[nt];
    }
}

// K2: e_exp = exp(e_t + Va_b); inv_denom[b] = 1/(sum + EPS)
__global__ __launch_bounds__(256) void k_denom(
    const float* __restrict__ e_t,
    const float* __restrict__ Va_b,
    float* __restrict__ e_exp,
    float* __restrict__ inv_denom)
{
    const int b = blockIdx.x;
    const int tid = threadIdx.x;
    const float vb = Va_b[0];
    float s = 0.0f;
#pragma unroll
    for (int i = 0; i < HW / 256; ++i) {
        const int idx = b * HW + i * 256 + tid;
        float e = __expf(e_t[idx] + vb);
        e_exp[idx] = e;
        s += e;
    }
#pragma unroll
    for (int off = 32; off > 0; off >>= 1) s += __shfl_down(s, off, 64);
    __shared__ float wsum[4];
    if ((tid & 63) == 0) wsum[tid >> 6] = s;
    __syncthreads();
    if (tid == 0) {
        float t = (wsum[0] + wsum[1]) + (wsum[2] + wsum[3]);
        inv_denom[b] = 1.0f / (t + EPS);
    }
}

// K3: out[b,c,p] = feature[b,c,p] * e_exp[b,p] * inv_denom[b]  (float4)
__global__ __launch_bounds__(256) void k_scale(
    const float* __restrict__ feature,
    const float* __restrict__ e_exp,
    const float* __restrict__ inv_denom,
    float* __restrict__ out)
{
    const int idx = blockIdx.x * 256 + threadIdx.x;   // float4 index
    const int pq = idx & (HW / 4 - 1);
    const int bc = idx >> 10;
    const int b  = bc >> 6;

    const float sc = inv_denom[b];
    const float4 e = ((const float4*)(e_exp + (size_t)b * HW))[pq];
    const float4 f = ((const float4*)feature)[idx];
    float4 o;
    o.x = f.x * (e.x * sc);
    o.y = f.y * (e.y * sc);
    o.z = f.z * (e.z * sc);
    o.w = f.w * (e.w * sc);
    ((float4*)out)[idx] = o;
}

extern "C" void kernel_launch(void* const* d_in, const int* in_sizes, int n_in,
                              void* d_out, int out_size, void* d_ws, size_t ws_size,
                              hipStream_t stream)
{
    const float* feature = (const float*)d_in[0];
    const float* query   = (const float*)d_in[1];
    const float* key     = (const float*)d_in[2];
    const float* Ua_w    = (const float*)d_in[3];
    const float* Ua_b    = (const float*)d_in[4];
    const float* Va_w    = (const float*)d_in[5];
    const float* Va_b    = (const float*)d_in[6];

    // workspace layout
    ushort_t* Whi = (ushort_t*)d_ws;                    // 512*64
    ushort_t* Wlo = Whi + NP * CH;                      // 512*64
    float* QB     = (float*)(Wlo + NP * CH);            // 32*512
    float* e_t    = QB + BSZ * NP;                      // 32*4096
    float* e_exp  = e_t + BSZ * HW;                     // 32*4096
    float* inv_denom = e_exp + BSZ * HW;                // 32

    k_prep<<<(NP * CH) / 256, 256, 0, stream>>>(Ua_w, Ua_b, query, Whi, Wlo, QB);
    k_scores<<<BSZ * (HW / 128), 256, 0, stream>>>(key, Whi, Wlo, QB, Va_w, e_t);
    k_denom<<<BSZ, 256, 0, stream>>>(e_t, Va_b, e_exp, inv_denom);
    k_scale<<<(BSZ * CH * HW / 4) / 256, 256, 0, stream>>>(feature, e_exp, inv_denom, (float*)d_out);
}

// Round 5
// 77.860 us; speedup vs baseline: 1.1764x; 1.1764x over previous
//
#include <hip/hip_runtime.h>

typedef unsigned short ushort_t;
typedef unsigned int uint_t;

constexpr int BSZ = 32;
constexpr int CH  = 64;
constexpr int HW  = 32 * 128;   // 4096
constexpr int NP  = 512;
constexpr int OSPLIT = 2;             // o-loop split across blocks
constexpr int OCHUNK = NP / OSPLIT;   // 256
constexpr float EPS = 1e-8f;

using short8 = __attribute__((ext_vector_type(8))) short;   // 8 bf16 (4 VGPRs)
using f32x4  = __attribute__((ext_vector_type(4))) float;

__device__ __forceinline__ ushort_t f2bf(float f) {   // fp32 -> bf16 RNE
    uint_t u = __builtin_bit_cast(uint_t, f);
    u += 0x7FFFu + ((u >> 16) & 1u);
    return (ushort_t)(u >> 16);
}
__device__ __forceinline__ float bf2f(ushort_t b) {
    uint_t u = ((uint_t)b) << 16;
    return __builtin_bit_cast(float, u);
}
__device__ __forceinline__ float tanh_fast(float x) {
    // tanh(x) = 1 - 2/(exp2(2*log2e*x)+1); 1 mul + 1 trans + 1 add + 1 trans + 1 fma
    float e = __builtin_amdgcn_exp2f(x * 2.8853900817779268f);
    float r = __builtin_amdgcn_rcpf(e + 1.0f);
    return fmaf(-2.0f, r, 1.0f);
}

// K0: split W into bf16 hi/lo; fold Ua_b+query into QB.
__global__ __launch_bounds__(256) void k_prep(
    const float* __restrict__ Ua_w, const float* __restrict__ Ua_b,
    const float* __restrict__ query,
    ushort_t* __restrict__ Whi, ushort_t* __restrict__ Wlo,
    float* __restrict__ QB)
{
    const int i = blockIdx.x * 256 + threadIdx.x;
    if (i < NP * CH) {
        float x = Ua_w[i];
        ushort_t h = f2bf(x);
        Whi[i] = h;
        Wlo[i] = f2bf(x - bf2f(h));
    }
    if (i < BSZ * NP) {
        QB[i] = query[i] + Ua_b[i & (NP - 1)];
    }
}

// K1: partial logits, MFMA 16x16x32 bf16, 3-pass bf16 split.
// Wave owns 64 positions (nt=4: 4 independent MFMA chains -- round-4 showed
// nt=2 starves ILP and stalls every pipe). Block covers OCHUNK=256 of the 512
// o's; grid = 32 b x 16 pc x 2 r = 1024 blocks -> 4 waves/SIMD at ~90 VGPR.
__global__ __launch_bounds__(256, 4) void k_scores(
    const float* __restrict__ key,
    const ushort_t* __restrict__ Whi, const ushort_t* __restrict__ Wlo,
    const float* __restrict__ QB, const float* __restrict__ Va_w,
    float* __restrict__ e_part)
{
    const int bx = blockIdx.x;            // 0..1023
    const int pc = bx & 15;               // position chunk
    const int b  = (bx >> 4) & 31;        // batch
    const int r  = bx >> 9;               // o-half
    const int wv = threadIdx.x >> 6;
    const int l  = threadIdx.x & 63;
    const int lm = l & 15;                // col-in-tile (A row / B,C col)
    const int kg = l >> 4;                // k-group
    const int p0 = pc * 256 + wv * 64;    // wave's first position

    // ---- load + bf16-split this wave's B = key[b, :, p0..p0+63] ----
    // B-frag layout: col = l&15, k = kg*8 + j  (within each K=32 step)
    short8 Bh[4][2], Bl[4][2];
    const float* kb = key + (size_t)b * CH * HW;
#pragma unroll
    for (int nt = 0; nt < 4; ++nt) {
#pragma unroll
        for (int ks = 0; ks < 2; ++ks) {
#pragma unroll
            for (int j = 0; j < 8; ++j) {
                float x = kb[(size_t)(ks * 32 + kg * 8 + j) * HW + (p0 + nt * 16 + lm)];
                ushort_t h = f2bf(x);
                Bh[nt][ks][j] = (short)h;
                Bl[nt][ks][j] = (short)f2bf(x - bf2f(h));
            }
        }
    }

    const float* qbp = QB + b * NP + r * OCHUNK;
    const float* vwp = Va_w + r * OCHUNK;
    const ushort_t* whp = Whi + r * OCHUNK * CH;
    const ushort_t* wlp = Wlo + r * OCHUNK * CH;

    float ew[4] = {0.0f, 0.0f, 0.0f, 0.0f};

#pragma unroll 2
    for (int mt = 0; mt < OCHUNK / 16; ++mt) {
        // A-frags: row = l&15, k = kg*8+j, contiguous 8 bf16 -> one dwordx4
        const int arow = (mt * 16 + lm) * CH + kg * 8;
        const short8 Ah0 = *(const short8*)(whp + arow);
        const short8 Ah1 = *(const short8*)(whp + arow + 32);
        const short8 Al0 = *(const short8*)(wlp + arow);
        const short8 Al1 = *(const short8*)(wlp + arow + 32);

        // C/D layout: col = l&15, row = kg*4 + r  ->  o = mt*16 + kg*4 + row
        const f32x4 qb = *(const f32x4*)(qbp + mt * 16 + kg * 4);
        const f32x4 vw = *(const f32x4*)(vwp + mt * 16 + kg * 4);

        f32x4 acc[4];
#pragma unroll
        for (int nt = 0; nt < 4; ++nt) acc[nt] = qb;   // fold QB into init
#pragma unroll
        for (int nt = 0; nt < 4; ++nt) {
            acc[nt] = __builtin_amdgcn_mfma_f32_16x16x32_bf16(Ah0, Bh[nt][0], acc[nt], 0, 0, 0);
            acc[nt] = __builtin_amdgcn_mfma_f32_16x16x32_bf16(Ah1, Bh[nt][1], acc[nt], 0, 0, 0);
            acc[nt] = __builtin_amdgcn_mfma_f32_16x16x32_bf16(Ah0, Bl[nt][0], acc[nt], 0, 0, 0);
            acc[nt] = __builtin_amdgcn_mfma_f32_16x16x32_bf16(Ah1, Bl[nt][1], acc[nt], 0, 0, 0);
            acc[nt] = __builtin_amdgcn_mfma_f32_16x16x32_bf16(Al0, Bh[nt][0], acc[nt], 0, 0, 0);
            acc[nt] = __builtin_amdgcn_mfma_f32_16x16x32_bf16(Al1, Bh[nt][1], acc[nt], 0, 0, 0);
        }

#pragma unroll
        for (int nt = 0; nt < 4; ++nt) {
#pragma unroll
            for (int rr = 0; rr < 4; ++rr) {
                ew[nt] = fmaf(vw[rr], tanh_fast(acc[nt][rr]), ew[nt]);
            }
        }
    }

    // reduce over the 4 k-groups (rows live in lanes l, l^16, l^32, l^48)
#pragma unroll
    for (int nt = 0; nt < 4; ++nt) {
        ew[nt] += __shfl_xor(ew[nt], 16, 64);
        ew[nt] += __shfl_xor(ew[nt], 32, 64);
    }
    if (kg == 0) {
#pragma unroll
        for (int nt = 0; nt < 4; ++nt)
            e_part[(size_t)r * (BSZ * HW) + (size_t)b * HW + p0 + nt * 16 + lm] = ew[nt];
    }
}

// K2: combine o-halves, exp, per-batch denominator.
__global__ __launch_bounds__(256) void k_denom(
    const float* __restrict__ e_part,
    const float* __restrict__ Va_b,
    float* __restrict__ e_exp,
    float* __restrict__ inv_denom)
{
    const int b = blockIdx.x;
    const int tid = threadIdx.x;
    const float vb = Va_b[0];
    float s = 0.0f;
#pragma unroll
    for (int i = 0; i < HW / 256; ++i) {
        const int idx = b * HW + i * 256 + tid;
        float e = __expf((e_part[idx] + e_part[BSZ * HW + idx]) + vb);
        e_exp[idx] = e;
        s += e;
    }
#pragma unroll
    for (int off = 32; off > 0; off >>= 1) s += __shfl_down(s, off, 64);
    __shared__ float wsum[4];
    if ((tid & 63) == 0) wsum[tid >> 6] = s;
    __syncthreads();
    if (tid == 0) {
        float t = (wsum[0] + wsum[1]) + (wsum[2] + wsum[3]);
        inv_denom[b] = 1.0f / (t + EPS);
    }
}

// K3: out[b,c,p] = feature[b,c,p] * e_exp[b,p] * inv_denom[b]  (float4)
__global__ __launch_bounds__(256) void k_scale(
    const float* __restrict__ feature,
    const float* __restrict__ e_exp,
    const float* __restrict__ inv_denom,
    float* __restrict__ out)
{
    const int idx = blockIdx.x * 256 + threadIdx.x;   // float4 index
    const int pq = idx & (HW / 4 - 1);
    const int bc = idx >> 10;
    const int b  = bc >> 6;

    const float sc = inv_denom[b];
    const float4 e = ((const float4*)(e_exp + (size_t)b * HW))[pq];
    const float4 f = ((const float4*)feature)[idx];
    float4 o;
    o.x = f.x * (e.x * sc);
    o.y = f.y * (e.y * sc);
    o.z = f.z * (e.z * sc);
    o.w = f.w * (e.w * sc);
    ((float4*)out)[idx] = o;
}

extern "C" void kernel_launch(void* const* d_in, const int* in_sizes, int n_in,
                              void* d_out, int out_size, void* d_ws, size_t ws_size,
                              hipStream_t stream)
{
    const float* feature = (const float*)d_in[0];
    const float* query   = (const float*)d_in[1];
    const float* key     = (const float*)d_in[2];
    const float* Ua_w    = (const float*)d_in[3];
    const float* Ua_b    = (const float*)d_in[4];
    const float* Va_w    = (const float*)d_in[5];
    const float* Va_b    = (const float*)d_in[6];

    // workspace layout
    ushort_t* Whi = (ushort_t*)d_ws;                        // 512*64
    ushort_t* Wlo = Whi + NP * CH;                          // 512*64
    float* QB     = (float*)(Wlo + NP * CH);                // 32*512
    float* e_part = QB + BSZ * NP;                          // OSPLIT*32*4096
    float* e_exp  = e_part + (size_t)OSPLIT * BSZ * HW;     // 32*4096
    float* inv_denom = e_exp + BSZ * HW;                    // 32

    k_prep<<<(NP * CH) / 256, 256, 0, stream>>>(Ua_w, Ua_b, query, Whi, Wlo, QB);
    k_scores<<<BSZ * (HW / 256) * OSPLIT, 256, 0, stream>>>(
        key, Whi, Wlo, QB, Va_w, e_part);
    k_denom<<<BSZ, 256, 0, stream>>>(e_part, Va_b, e_exp, inv_denom);
    k_scale<<<(BSZ * CH * HW / 4) / 256, 256, 0, stream>>>(
        feature, e_exp, inv_denom, (float*)d_out);
}

// Round 6
// 66.280 us; speedup vs baseline: 1.3820x; 1.1747x over previous
//
#include <hip/hip_runtime.h>

typedef unsigned short ushort_t;
typedef unsigned int uint_t;

constexpr int BSZ = 32;
constexpr int CH  = 64;
constexpr int HW  = 32 * 128;   // 4096
constexpr int NP  = 512;
constexpr int OSPLIT = 2;             // o-loop split across blocks
constexpr int OCHUNK = NP / OSPLIT;   // 256
constexpr float EPS = 1e-8f;

using short8 = __attribute__((ext_vector_type(8))) short;   // 8 bf16 (4 VGPRs)
using f32x4  = __attribute__((ext_vector_type(4))) float;

__device__ __forceinline__ ushort_t f2bf(float f) {   // fp32 -> bf16 RNE
    uint_t u = __builtin_bit_cast(uint_t, f);
    u += 0x7FFFu + ((u >> 16) & 1u);
    return (ushort_t)(u >> 16);
}
__device__ __forceinline__ float bf2f(ushort_t b) {
    uint_t u = ((uint_t)b) << 16;
    return __builtin_bit_cast(float, u);
}
__device__ __forceinline__ float tanh_fast(float x) {
    // tanh(x) = 1 - 2/(exp2(2*log2e*x)+1)
    float e = __builtin_amdgcn_exp2f(x * 2.8853900817779268f);
    float r = __builtin_amdgcn_rcpf(e + 1.0f);
    return fmaf(-2.0f, r, 1.0f);
}

// K0: split W into bf16 hi/lo; fold Ua_b+query into QB.
__global__ __launch_bounds__(256) void k_prep(
    const float* __restrict__ Ua_w, const float* __restrict__ Ua_b,
    const float* __restrict__ query,
    ushort_t* __restrict__ Whi, ushort_t* __restrict__ Wlo,
    float* __restrict__ QB)
{
    const int i = blockIdx.x * 256 + threadIdx.x;
    if (i < NP * CH) {
        float x = Ua_w[i];
        ushort_t h = f2bf(x);
        Whi[i] = h;
        Wlo[i] = f2bf(x - bf2f(h));
    }
    if (i < BSZ * NP) {
        QB[i] = query[i] + Ua_b[i & (NP - 1)];
    }
}

// K1: partial logits, MFMA 16x16x32 bf16, 3-pass bf16 split.
// nt=4 (4 independent MFMA chains: covers MFMA latency; round-4's nt=2 did
// not). acc starts at 0 so no VMEM load sits on the MFMA serial path
// (round-4/5's qb-folded init put an L2 load there); qb is added in the
// epilogue. A-frags/qb/vw software-pipelined one m-tile ahead.
// launch_bounds(256,3): ~170 VGPR cap -- (256,4) made the compiler spill
// the 64 B-frag VGPRs (round 5: VGPR=64 reported, 38 MB scratch writes).
__global__ __launch_bounds__(256, 3) void k_scores(
    const float* __restrict__ key,
    const ushort_t* __restrict__ Whi, const ushort_t* __restrict__ Wlo,
    const float* __restrict__ QB, const float* __restrict__ Va_w,
    float* __restrict__ e_part)
{
    const int bx = blockIdx.x;            // 0..1023
    const int pc = bx & 15;               // position chunk
    const int b  = (bx >> 4) & 31;        // batch
    const int r  = bx >> 9;               // o-half
    const int wv = threadIdx.x >> 6;
    const int l  = threadIdx.x & 63;
    const int lm = l & 15;                // col-in-tile (A row / B,C col)
    const int kg = l >> 4;                // k-group
    const int p0 = pc * 256 + wv * 64;    // wave's first position

    // ---- load + bf16-split this wave's B = key[b, :, p0..p0+63] ----
    short8 Bh[4][2], Bl[4][2];
    const float* kb = key + (size_t)b * CH * HW;
#pragma unroll
    for (int nt = 0; nt < 4; ++nt) {
#pragma unroll
        for (int ks = 0; ks < 2; ++ks) {
#pragma unroll
            for (int j = 0; j < 8; ++j) {
                float x = kb[(size_t)(ks * 32 + kg * 8 + j) * HW + (p0 + nt * 16 + lm)];
                ushort_t h = f2bf(x);
                Bh[nt][ks][j] = (short)h;
                Bl[nt][ks][j] = (short)f2bf(x - bf2f(h));
            }
        }
    }

    const float* qbp = QB + b * NP + r * OCHUNK;
    const float* vwp = Va_w + r * OCHUNK;
    const ushort_t* whp = Whi + r * OCHUNK * CH;
    const ushort_t* wlp = Wlo + r * OCHUNK * CH;

    float ew[4] = {0.0f, 0.0f, 0.0f, 0.0f};

    // software pipeline: prefetch m-tile 0
    int arow = lm * CH + kg * 8;
    short8 nAh0 = *(const short8*)(whp + arow);
    short8 nAh1 = *(const short8*)(whp + arow + 32);
    short8 nAl0 = *(const short8*)(wlp + arow);
    short8 nAl1 = *(const short8*)(wlp + arow + 32);
    f32x4 nqb = *(const f32x4*)(qbp + kg * 4);
    f32x4 nvw = *(const f32x4*)(vwp + kg * 4);

    for (int mt = 0; mt < OCHUNK / 16; ++mt) {
        const short8 Ah0 = nAh0, Ah1 = nAh1, Al0 = nAl0, Al1 = nAl1;
        const f32x4 qb = nqb, vw = nvw;
        if (mt + 1 < OCHUNK / 16) {       // prefetch m-tile mt+1
            arow = ((mt + 1) * 16 + lm) * CH + kg * 8;
            nAh0 = *(const short8*)(whp + arow);
            nAh1 = *(const short8*)(whp + arow + 32);
            nAl0 = *(const short8*)(wlp + arow);
            nAl1 = *(const short8*)(wlp + arow + 32);
            nqb = *(const f32x4*)(qbp + (mt + 1) * 16 + kg * 4);
            nvw = *(const f32x4*)(vwp + (mt + 1) * 16 + kg * 4);
        }

        f32x4 acc[4];
#pragma unroll
        for (int nt = 0; nt < 4; ++nt) acc[nt] = (f32x4){0.f, 0.f, 0.f, 0.f};
#pragma unroll
        for (int nt = 0; nt < 4; ++nt) {
            acc[nt] = __builtin_amdgcn_mfma_f32_16x16x32_bf16(Ah0, Bh[nt][0], acc[nt], 0, 0, 0);
            acc[nt] = __builtin_amdgcn_mfma_f32_16x16x32_bf16(Ah1, Bh[nt][1], acc[nt], 0, 0, 0);
            acc[nt] = __builtin_amdgcn_mfma_f32_16x16x32_bf16(Ah0, Bl[nt][0], acc[nt], 0, 0, 0);
            acc[nt] = __builtin_amdgcn_mfma_f32_16x16x32_bf16(Ah1, Bl[nt][1], acc[nt], 0, 0, 0);
            acc[nt] = __builtin_amdgcn_mfma_f32_16x16x32_bf16(Al0, Bh[nt][0], acc[nt], 0, 0, 0);
            acc[nt] = __builtin_amdgcn_mfma_f32_16x16x32_bf16(Al1, Bh[nt][1], acc[nt], 0, 0, 0);
        }

        // C/D layout: col = l&15, row = kg*4 + rr  ->  o = mt*16 + kg*4 + rr
#pragma unroll
        for (int nt = 0; nt < 4; ++nt) {
#pragma unroll
            for (int rr = 0; rr < 4; ++rr) {
                float s = acc[nt][rr] + qb[rr];
                ew[nt] = fmaf(vw[rr], tanh_fast(s), ew[nt]);
            }
        }
    }

    // reduce over the 4 k-groups (rows live in lanes l, l^16, l^32, l^48)
#pragma unroll
    for (int nt = 0; nt < 4; ++nt) {
        ew[nt] += __shfl_xor(ew[nt], 16, 64);
        ew[nt] += __shfl_xor(ew[nt], 32, 64);
    }
    if (kg == 0) {
#pragma unroll
        for (int nt = 0; nt < 4; ++nt)
            e_part[(size_t)r * (BSZ * HW) + (size_t)b * HW + p0 + nt * 16 + lm] = ew[nt];
    }
}

// K2: combine o-halves, exp, per-batch denominator.
__global__ __launch_bounds__(256) void k_denom(
    const float* __restrict__ e_part,
    const float* __restrict__ Va_b,
    float* __restrict__ e_exp,
    float* __restrict__ inv_denom)
{
    const int b = blockIdx.x;
    const int tid = threadIdx.x;
    const float vb = Va_b[0];
    float s = 0.0f;
#pragma unroll
    for (int i = 0; i < HW / 256; ++i) {
        const int idx = b * HW + i * 256 + tid;
        float e = __expf((e_part[idx] + e_part[BSZ * HW + idx]) + vb);
        e_exp[idx] = e;
        s += e;
    }
#pragma unroll
    for (int off = 32; off > 0; off >>= 1) s += __shfl_down(s, off, 64);
    __shared__ float wsum[4];
    if ((tid & 63) == 0) wsum[tid >> 6] = s;
    __syncthreads();
    if (tid == 0) {
        float t = (wsum[0] + wsum[1]) + (wsum[2] + wsum[3]);
        inv_denom[b] = 1.0f / (t + EPS);
    }
}

// K3: out[b,c,p] = feature[b,c,p] * e_exp[b,p] * inv_denom[b]  (float4)
__global__ __launch_bounds__(256) void k_scale(
    const float* __restrict__ feature,
    const float* __restrict__ e_exp,
    const float* __restrict__ inv_denom,
    float* __restrict__ out)
{
    const int idx = blockIdx.x * 256 + threadIdx.x;   // float4 index
    const int pq = idx & (HW / 4 - 1);
    const int bc = idx >> 10;
    const int b  = bc >> 6;

    const float sc = inv_denom[b];
    const float4 e = ((const float4*)(e_exp + (size_t)b * HW))[pq];
    const float4 f = ((const float4*)feature)[idx];
    float4 o;
    o.x = f.x * (e.x * sc);
    o.y = f.y * (e.y * sc);
    o.z = f.z * (e.z * sc);
    o.w = f.w * (e.w * sc);
    ((float4*)out)[idx] = o;
}

extern "C" void kernel_launch(void* const* d_in, const int* in_sizes, int n_in,
                              void* d_out, int out_size, void* d_ws, size_t ws_size,
                              hipStream_t stream)
{
    const float* feature = (const float*)d_in[0];
    const float* query   = (const float*)d_in[1];
    const float* key     = (const float*)d_in[2];
    const float* Ua_w    = (const float*)d_in[3];
    const float* Ua_b    = (const float*)d_in[4];
    const float* Va_w    = (const float*)d_in[5];
    const float* Va_b    = (const float*)d_in[6];

    // workspace layout
    ushort_t* Whi = (ushort_t*)d_ws;                        // 512*64
    ushort_t* Wlo = Whi + NP * CH;                          // 512*64
    float* QB     = (float*)(Wlo + NP * CH);                // 32*512
    float* e_part = QB + BSZ * NP;                          // OSPLIT*32*4096
    float* e_exp  = e_part + (size_t)OSPLIT * BSZ * HW;     // 32*4096
    float* inv_denom = e_exp + BSZ * HW;                    // 32

    k_prep<<<(NP * CH) / 256, 256, 0, stream>>>(Ua_w, Ua_b, query, Whi, Wlo, QB);
    k_scores<<<BSZ * (HW / 256) * OSPLIT, 256, 0, stream>>>(
        key, Whi, Wlo, QB, Va_w, e_part);
    k_denom<<<BSZ, 256, 0, stream>>>(e_part, Va_b, e_exp, inv_denom);
    k_scale<<<(BSZ * CH * HW / 4) / 256, 256, 0, stream>>>(
        feature, e_exp, inv_denom, (float*)d_out);
}